// Round 3
// baseline (43.570 us; speedup 1.0000x reference)
//
#include <hip/hip_runtime.h>

// IF neuron forward: X [B=64, T=32, N=16384] f32 -> spikes [B, T, N] f32.
// Memory-bound: 128 MiB read + 128 MiB write. Strategy: keep input L3-resident
// across graph replays by streaming the output with sc0+sc1+nt stores
// (system-coherent write-through + nontemporal -> no L2/L3 allocate), so the
// write stream stops evicting the input from Infinity Cache.
// float4 per lane (16 B) for widest coalesced transactions.

#define B_DIM 64
#define T_DIM 32
#define N_DIM 16384

typedef float f32x4 __attribute__((ext_vector_type(4)));

__global__ __launch_bounds__(256) void if_forward_kernel(
    const float* __restrict__ X, float* __restrict__ out) {
    const int n4 = N_DIM / 4;                        // float4 groups per row
    int idx = blockIdx.x * blockDim.x + threadIdx.x; // [0, B*n4)
    if (idx >= B_DIM * n4) return;

    int b = idx / n4;
    int g = idx - b * n4;
    size_t base = (size_t)b * T_DIM * N_DIM + (size_t)g * 4;

    f32x4 mem = {0.f, 0.f, 0.f, 0.f};

    #pragma unroll
    for (int t = 0; t < T_DIM; ++t) {
        size_t off = base + (size_t)t * N_DIM;
        f32x4 x = *reinterpret_cast<const f32x4*>(X + off);
        f32x4 s;

        mem.x += x.x; s.x = (mem.x > 1.0f) ? 1.0f : 0.0f; mem.x = (mem.x > 1.0f) ? 0.0f : mem.x;
        mem.y += x.y; s.y = (mem.y > 1.0f) ? 1.0f : 0.0f; mem.y = (mem.y > 1.0f) ? 0.0f : mem.y;
        mem.z += x.z; s.z = (mem.z > 1.0f) ? 1.0f : 0.0f; mem.z = (mem.z > 1.0f) ? 0.0f : mem.z;
        mem.w += x.w; s.w = (mem.w > 1.0f) ? 1.0f : 0.0f; mem.w = (mem.w > 1.0f) ? 0.0f : mem.w;

        // Streaming store: sc0 sc1 nt = system-coherent write-through,
        // nontemporal -> request no-allocate in L2/Infinity Cache.
        const float* p = out + off;
        asm volatile("global_store_dwordx4 %0, %1, off sc0 sc1 nt"
                     :: "v"(p), "v"(s) : "memory");
    }
}

extern "C" void kernel_launch(void* const* d_in, const int* in_sizes, int n_in,
                              void* d_out, int out_size, void* d_ws, size_t ws_size,
                              hipStream_t stream) {
    const float* X = (const float*)d_in[0];
    float* out = (float*)d_out;

    const int total_threads = B_DIM * (N_DIM / 4);   // 262,144
    const int block = 256;
    const int grid = (total_threads + block - 1) / block;  // 1024
    if_forward_kernel<<<grid, block, 0, stream>>>(X, out);
}